// Round 2
// baseline (1049.105 us; speedup 1.0000x reference)
//
#include <hip/hip_runtime.h>
#include <hip/hip_bf16.h>

static constexpr int TOTAL = 349525;
static constexpr int OFFS[11] = {0,1,5,21,85,341,1365,5461,21845,87381,349525};
// emb blocks of 128 nodes per level: counts {1,1,1,1,2,8,32,128,512,2048}
static constexpr int EBLK[11] = {0,1,2,3,4,6,14,46,174,686,2734};

__device__ __forceinline__ unsigned deint(unsigned v){
  v &= 0x55555555u;
  v = (v | (v>>1)) & 0x33333333u;
  v = (v | (v>>2)) & 0x0F0F0F0Fu;
  v = (v | (v>>4)) & 0x00FF00FFu;
  v = (v | (v>>8)) & 0x0000FFFFu;
  return v;
}
__device__ __forceinline__ unsigned ileave(unsigned v){
  v &= 0xFFFFu;
  v = (v | (v<<8)) & 0x00FF00FFu;
  v = (v | (v<<4)) & 0x0F0F0F0Fu;
  v = (v | (v<<2)) & 0x33333333u;
  v = (v | (v<<1)) & 0x55555555u;
  return v;
}

// input column k (0..39) for global node g: [feat, x, y, dn, sin/cos enc(36)]
__device__ float inproj_input(int g, int k, const float* __restrict__ feat){
  if (k == 0) return feat[g];
  int d = 0;
  #pragma unroll
  for (int i = 1; i <= 9; ++i) if (g >= OFFS[i]) d = i;
  int local = g - OFFS[d];
  unsigned ix = deint((unsigned)local), iy = deint(((unsigned)local) >> 1);
  float res = (float)(1 << d);
  float px = ((float)ix + 0.5f) / res;
  float py = ((float)iy + 0.5f) / res;
  float pd = (float)d * (1.0f / 9.0f);
  if (k == 1) return px;
  if (k == 2) return py;
  if (k == 3) return pd;
  int e = k - 4;
  int c = e / 12, r = e % 12;
  float p = (c == 0) ? px : (c == 1) ? py : pd;
  float ang = p * 6.28318530717958647692f * (float)(1 << (r % 6));
  return (r < 6) ? sinf(ang) : cosf(ang);
}

// ---------- in_proj: h[g] = concat(f, posenc) @ W(40x64) + b ----------
__global__ __launch_bounds__(256) void k_inproj(const float* __restrict__ feat,
    const float* __restrict__ W, const float* __restrict__ B, float* __restrict__ h){
  __shared__ float Al[40][128];   // [k][node]
  __shared__ float Wl[40][68];    // [k][ch], pitch 68 (16B-aligned rows)
  int t = threadIdx.x;
  int base = blockIdx.x * 128;
  for (int idx = t; idx < 40*64; idx += 256){
    int k = idx >> 6, c = idx & 63;
    Wl[k][c] = W[idx];
  }
  for (int idx = t; idx < 40*128; idx += 256){
    int k = idx >> 7, node = idx & 127;
    int g = base + node;
    Al[k][node] = (g < TOTAL) ? inproj_input(g, k, feat) : 0.f;
  }
  __syncthreads();
  int tr = t >> 3, tc = t & 7;        // 4 nodes x 8 ch per thread
  float acc[4][8];
  #pragma unroll
  for (int i=0;i<4;++i)
    #pragma unroll
    for (int c=0;c<8;++c) acc[i][c] = 0.f;
  #pragma unroll 4
  for (int k=0;k<40;++k){
    float4 a = *(const float4*)&Al[k][tr*4];
    float w[8];
    *(float4*)&w[0] = *(const float4*)&Wl[k][tc*8];
    *(float4*)&w[4] = *(const float4*)&Wl[k][tc*8+4];
    #pragma unroll
    for (int c=0;c<8;++c){
      acc[0][c] += a.x * w[c];
      acc[1][c] += a.y * w[c];
      acc[2][c] += a.z * w[c];
      acc[3][c] += a.w * w[c];
    }
  }
  float bias[8];
  #pragma unroll
  for (int c=0;c<8;++c) bias[c] = B[tc*8+c];
  #pragma unroll
  for (int i=0;i<4;++i){
    int g = base + tr*4 + i;
    if (g >= TOTAL) continue;
    float ov[8];
    #pragma unroll
    for (int c=0;c<8;++c) ov[c] = acc[i][c] + bias[c];
    float* dst = &h[(size_t)g*64 + tc*8];
    *(float4*)dst       = *(const float4*)&ov[0];
    *(float4*)(dst + 4) = *(const float4*)&ov[4];
  }
}

// ---------- pool: hd1 = h[parent] + mean(children); to stg (or to h for level 0) ----------
__global__ __launch_bounds__(256) void k_pool(float* h, float* stg, int Np,
    int offPar, int offChild, int toH){
  int gid = blockIdx.x*256 + threadIdx.x;
  if (gid >= Np*64) return;
  int p = gid >> 6, ch = gid & 63;
  const float* c0 = h + (size_t)(offChild + 4*p)*64 + ch;
  float s = c0[0] + c0[64] + c0[128] + c0[192];
  float v = 0.25f*s + h[(size_t)(offPar + p)*64 + ch];
  if (toH) h[(size_t)(offPar + p)*64 + ch] = v;
  else stg[gid] = v;
}

// ---------- conv: h[L] = relu( gather9(stg) @ conv_W[L] + b ) ----------
__global__ __launch_bounds__(256) void k_conv(const float* __restrict__ A,
    const float* __restrict__ W, const float* __restrict__ B, float* __restrict__ h,
    int N, int off, int lbits){
  __shared__ float Al[64][129];   // [kk][node] pitch 129
  __shared__ float Wl[64][68];    // [kk][ch]
  __shared__ int nkey[128][9];
  int t = threadIdx.x;
  int nb = blockIdx.x * 128;
  if (t < 128){
    int node = nb + t;
    int res = 1 << lbits;
    bool ok = node < N;
    unsigned ix = 0, iy = 0;
    if (ok){ ix = deint((unsigned)node); iy = deint(((unsigned)node) >> 1); }
    #pragma unroll
    for (int m=0;m<9;++m){
      int dy = m/3 - 1, dx = m%3 - 1;
      int nx = (int)ix + dx, ny = (int)iy + dy;
      int key = -1;
      if (ok && nx>=0 && ny>=0 && nx<res && ny<res)
        key = (int)(ileave((unsigned)nx) | (ileave((unsigned)ny) << 1));
      nkey[t][m] = key;
    }
  }
  int tr = t >> 3, tc = t & 7;
  float acc[4][8];
  #pragma unroll
  for (int i=0;i<4;++i)
    #pragma unroll
    for (int c=0;c<8;++c) acc[i][c] = 0.f;
  for (int m=0;m<9;++m){
    __syncthreads();   // covers nkey (m=0) and previous compute
    for (int idx = t; idx < 128*64; idx += 256){
      int node = idx >> 6, kk = idx & 63;     // lanes = kk: coalesced 256B row gather
      int key = nkey[node][m];
      Al[kk][node] = (key >= 0) ? A[(size_t)key*64 + kk] : 0.f;
    }
    for (int idx = t; idx < 64*64; idx += 256){
      int kk = idx >> 6, c = idx & 63;
      Wl[kk][c] = W[(size_t)(m*64 + kk)*64 + c];
    }
    __syncthreads();
    #pragma unroll 4
    for (int kk=0;kk<64;++kk){
      float a0 = Al[kk][tr*4+0], a1 = Al[kk][tr*4+1];
      float a2 = Al[kk][tr*4+2], a3 = Al[kk][tr*4+3];
      float w[8];
      *(float4*)&w[0] = *(const float4*)&Wl[kk][tc*8];
      *(float4*)&w[4] = *(const float4*)&Wl[kk][tc*8+4];
      #pragma unroll
      for (int c=0;c<8;++c){
        acc[0][c] += a0 * w[c];
        acc[1][c] += a1 * w[c];
        acc[2][c] += a2 * w[c];
        acc[3][c] += a3 * w[c];
      }
    }
  }
  float bias[8];
  #pragma unroll
  for (int c=0;c<8;++c) bias[c] = B[tc*8+c];
  #pragma unroll
  for (int i=0;i<4;++i){
    int node = nb + tr*4 + i;
    if (node >= N) continue;
    float ov[8];
    #pragma unroll
    for (int c=0;c<8;++c){
      float v = acc[i][c] + bias[c];
      ov[c] = v > 0.f ? v : 0.f;
    }
    float* dst = &h[(size_t)(off + node)*64 + tc*8];
    *(float4*)dst       = *(const float4*)&ov[0];
    *(float4*)(dst + 4) = *(const float4*)&ov[4];
  }
}

// ---------- emb + layernorm + gain, in place over h ----------
__global__ __launch_bounds__(256) void k_emb(float* h, const float* __restrict__ embW,
    const float* __restrict__ embB, const float* __restrict__ lng,
    const float* __restrict__ lnb, const float* __restrict__ gain){
  int bb = blockIdx.x;
  int d = 0;
  #pragma unroll
  for (int i = 1; i <= 9; ++i) if (bb >= EBLK[i]) d = i;
  int nb = (bb - EBLK[d]) * 128;
  int N = 1 << (2*d);
  int off = OFFS[d];

  __shared__ float Al[64][129];   // [k][node]
  __shared__ float Wl[64][68];    // [k][ch]
  int t = threadIdx.x;
  for (int idx = t; idx < 64*128; idx += 256){
    int k = idx & 63, node = idx >> 6;       // lanes = k: coalesced 256B row reads
    int g = nb + node;
    Al[k][node] = (g < N) ? h[(size_t)(off + g)*64 + k] : 0.f;
  }
  const float* Wd = embW + (size_t)d*64*64;
  for (int idx = t; idx < 64*64; idx += 256){
    int k = idx >> 6, c = idx & 63;
    Wl[k][c] = Wd[k*64 + c];
  }
  __syncthreads();
  int tr = t >> 3, tc = t & 7;
  float acc[4][8];
  #pragma unroll
  for (int i=0;i<4;++i)
    #pragma unroll
    for (int c=0;c<8;++c) acc[i][c] = embB[d*64 + tc*8 + c];
  #pragma unroll 4
  for (int k=0;k<64;++k){
    float a0 = Al[k][tr*4+0], a1 = Al[k][tr*4+1];
    float a2 = Al[k][tr*4+2], a3 = Al[k][tr*4+3];
    float w[8];
    *(float4*)&w[0] = *(const float4*)&Wl[k][tc*8];
    *(float4*)&w[4] = *(const float4*)&Wl[k][tc*8+4];
    #pragma unroll
    for (int c=0;c<8;++c){
      acc[0][c] += a0 * w[c];
      acc[1][c] += a1 * w[c];
      acc[2][c] += a2 * w[c];
      acc[3][c] += a3 * w[c];
    }
  }
  float gvals[8], bvals[8];
  #pragma unroll
  for (int c=0;c<8;++c){
    gvals[c] = lng[d*64 + tc*8 + c];
    bvals[c] = lnb[d*64 + tc*8 + c];
  }
  float gn = gain[d];
  #pragma unroll
  for (int i=0;i<4;++i){
    float s = 0.f, q = 0.f;
    #pragma unroll
    for (int c=0;c<8;++c){ s += acc[i][c]; q += acc[i][c]*acc[i][c]; }
    // reduce across the 8 tc lanes (lane bits 0..2) holding this node's 64 channels
    #pragma unroll
    for (int msk = 1; msk < 8; msk <<= 1){
      s += __shfl_xor(s, msk, 64);
      q += __shfl_xor(q, msk, 64);
    }
    float mu = s * 0.015625f;
    float var = q * 0.015625f - mu*mu;
    float rs = rsqrtf(var + 1e-5f);
    int node = nb + tr*4 + i;
    if (node < N){
      float ov[8];
      #pragma unroll
      for (int c=0;c<8;++c)
        ov[c] = ((acc[i][c] - mu) * rs * gvals[c] + bvals[c]) * gn;
      float* dst = &h[(size_t)(off + node)*64 + tc*8];
      *(float4*)dst       = *(const float4*)&ov[0];
      *(float4*)(dst + 4) = *(const float4*)&ov[4];
    }
  }
}

extern "C" void kernel_launch(void* const* d_in, const int* in_sizes, int n_in,
                              void* d_out, int out_size, void* d_ws, size_t ws_size,
                              hipStream_t stream) {
  (void)in_sizes; (void)n_in; (void)out_size; (void)ws_size;
  const float* feat  = (const float*)d_in[0];
  const float* ipW   = (const float*)d_in[1];
  const float* ipB   = (const float*)d_in[2];
  const float* convW = (const float*)d_in[3];
  const float* convB = (const float*)d_in[4];
  const float* embW  = (const float*)d_in[5];
  const float* embB  = (const float*)d_in[6];
  const float* lng   = (const float*)d_in[7];
  const float* lnb   = (const float*)d_in[8];
  const float* gain  = (const float*)d_in[9];
  float* h   = (float*)d_out;          // h lives in d_out (f32), emb runs in place
  float* stg = (float*)d_ws;           // f32 hd1 staging, max 4^8*64*4 = 16.8 MB

  k_inproj<<<(TOTAL + 127)/128, 256, 0, stream>>>(feat, ipW, ipB, h);

  for (int d = 9; d >= 1; --d){
    int L = d - 1;
    int Np = 1 << (2*L);
    int blocks = (Np*64 + 255)/256;
    k_pool<<<blocks, 256, 0, stream>>>(h, stg, Np, OFFS[L], OFFS[d], L == 0 ? 1 : 0);
    if (L >= 1){
      k_conv<<<(Np + 127)/128, 256, 0, stream>>>(stg,
          convW + (size_t)L*576*64, convB + (size_t)L*64, h, Np, OFFS[L], L);
    }
  }

  k_emb<<<2734, 256, 0, stream>>>(h, embW, embB, lng, lnb, gain);
}

// Round 3
// 568.992 us; speedup vs baseline: 1.8438x; 1.8438x over previous
//
#include <hip/hip_runtime.h>
#include <hip/hip_bf16.h>

static constexpr int TOTAL = 349525;
static constexpr int OFFS[11] = {0,1,5,21,85,341,1365,5461,21845,87381,349525};
// emb blocks of 128 nodes per level: counts {1,1,1,1,2,8,32,128,512,2048}
static constexpr int EBLK[11] = {0,1,2,3,4,6,14,46,174,686,2734};

__device__ __forceinline__ unsigned deint(unsigned v){
  v &= 0x55555555u;
  v = (v | (v>>1)) & 0x33333333u;
  v = (v | (v>>2)) & 0x0F0F0F0Fu;
  v = (v | (v>>4)) & 0x00FF00FFu;
  v = (v | (v>>8)) & 0x0000FFFFu;
  return v;
}
__device__ __forceinline__ unsigned ileave(unsigned v){
  v &= 0xFFFFu;
  v = (v | (v<<8)) & 0x00FF00FFu;
  v = (v | (v<<4)) & 0x0F0F0F0Fu;
  v = (v | (v<<2)) & 0x33333333u;
  v = (v | (v<<1)) & 0x55555555u;
  return v;
}

// input column k (0..39) for global node g: [feat, x, y, dn, sin/cos enc(36)]
__device__ float inproj_input(int g, int k, const float* __restrict__ feat){
  if (k == 0) return feat[g];
  int d = 0;
  #pragma unroll
  for (int i = 1; i <= 9; ++i) if (g >= OFFS[i]) d = i;
  int local = g - OFFS[d];
  unsigned ix = deint((unsigned)local), iy = deint(((unsigned)local) >> 1);
  float res = (float)(1 << d);
  float px = ((float)ix + 0.5f) / res;
  float py = ((float)iy + 0.5f) / res;
  float pd = (float)d * (1.0f / 9.0f);
  if (k == 1) return px;
  if (k == 2) return py;
  if (k == 3) return pd;
  int e = k - 4;
  int c = e / 12, r = e % 12;
  float p = (c == 0) ? px : (c == 1) ? py : pd;
  float ang = p * 6.28318530717958647692f * (float)(1 << (r % 6));
  return (r < 6) ? sinf(ang) : cosf(ang);
}

// ---------- in_proj: h[g] = concat(f, posenc) @ W(40x64) + b ----------
__global__ __launch_bounds__(256) void k_inproj(const float* __restrict__ feat,
    const float* __restrict__ W, const float* __restrict__ B, float* __restrict__ h){
  __shared__ float Al[40][128];   // [k][node], rows 16B-aligned
  __shared__ float Wl[40][68];    // [k][ch]
  int t = threadIdx.x;
  int base = blockIdx.x * 128;
  for (int idx = t; idx < 40*64; idx += 256){
    int k = idx >> 6, c = idx & 63;
    Wl[k][c] = W[idx];
  }
  for (int idx = t; idx < 40*128; idx += 256){
    int k = idx >> 7, node = idx & 127;
    int g = base + node;
    Al[k][node] = (g < TOTAL) ? inproj_input(g, k, feat) : 0.f;
  }
  __syncthreads();
  int tr = t >> 3, tc = t & 7;        // 4 nodes x 8 ch per thread
  float acc[4][8];
  #pragma unroll
  for (int i=0;i<4;++i)
    #pragma unroll
    for (int c=0;c<8;++c) acc[i][c] = 0.f;
  #pragma unroll 4
  for (int k=0;k<40;++k){
    float4 a = *(const float4*)&Al[k][tr*4];
    float w[8];
    *(float4*)&w[0] = *(const float4*)&Wl[k][tc*8];
    *(float4*)&w[4] = *(const float4*)&Wl[k][tc*8+4];
    #pragma unroll
    for (int c=0;c<8;++c){
      acc[0][c] += a.x * w[c];
      acc[1][c] += a.y * w[c];
      acc[2][c] += a.z * w[c];
      acc[3][c] += a.w * w[c];
    }
  }
  float bias[8];
  #pragma unroll
  for (int c=0;c<8;++c) bias[c] = B[tc*8+c];
  #pragma unroll
  for (int i=0;i<4;++i){
    int g = base + tr*4 + i;
    if (g >= TOTAL) continue;
    float ov[8];
    #pragma unroll
    for (int c=0;c<8;++c) ov[c] = acc[i][c] + bias[c];
    float* dst = &h[(size_t)g*64 + tc*8];
    *(float4*)dst       = *(const float4*)&ov[0];
    *(float4*)(dst + 4) = *(const float4*)&ov[4];
  }
}

// ---------- pool: stg[p] = h[parent p] + mean(children) ----------
__global__ __launch_bounds__(256) void k_pool(const float* __restrict__ h,
    float* __restrict__ stg, int Np, int offPar, int offChild){
  int gid = blockIdx.x*256 + threadIdx.x;
  if (gid >= Np*64) return;
  int p = gid >> 6, ch = gid & 63;
  const float* c0 = h + (size_t)(offChild + 4*p)*64 + ch;
  float s = c0[0] + c0[64] + c0[128] + c0[192];
  stg[gid] = 0.25f*s + h[(size_t)(offPar + p)*64 + ch];
}

// ---------- conv: h[L] = relu( gather9(stg) @ conv_W[L] + b ), T14 pipelined ----------
template<int NPB>   // nodes per block: 128 (L=8) or 64 (L<=7)
__global__ __launch_bounds__(256, 3) void k_conv(const float* __restrict__ A,
    const float* __restrict__ W, const float* __restrict__ Bb, float* __restrict__ h,
    int N, int off, int lbits){
  constexpr int R  = NPB/32;        // nodes per thread
  constexpr int LA = NPB*64/256;    // gathered elements per thread (32 or 16)
  __shared__ float Al[64][NPB+1];   // [kk][node]
  __shared__ float Wl[64][68];      // [kk][ch]
  __shared__ unsigned short kkey[NPB][9];
  __shared__ unsigned short kmsk[NPB];
  int t = threadIdx.x;
  int nb = blockIdx.x * NPB;
  if (t < NPB){
    int node = nb + t;
    int res = 1 << lbits;
    bool ok = node < N;
    unsigned ix = 0, iy = 0;
    if (ok){ ix = deint((unsigned)node); iy = deint(((unsigned)node) >> 1); }
    unsigned msk = 0;
    #pragma unroll
    for (int m=0;m<9;++m){
      int dy = m/3 - 1, dx = m%3 - 1;
      int nx = (int)ix + dx, ny = (int)iy + dy;
      unsigned key = 0;
      if (ok && nx>=0 && ny>=0 && nx<res && ny<res){
        key = ileave((unsigned)nx) | (ileave((unsigned)ny) << 1);
        msk |= (1u << m);
      }
      kkey[t][m] = (unsigned short)key;
    }
    kmsk[t] = (unsigned short)msk;
  }
  __syncthreads();

  float rA[LA];
  float4 rW[4];
  auto pref = [&](int m){
    #pragma unroll
    for (int j=0;j<LA;++j){
      int e = t + j*256;
      int node = e >> 6, kk = e & 63;
      bool v = (kmsk[node] >> m) & 1;
      unsigned key = kkey[node][m];
      rA[j] = v ? A[(size_t)key*64 + kk] : 0.f;
    }
    const float4* W4 = (const float4*)(W + (size_t)m*4096);
    #pragma unroll
    for (int j=0;j<4;++j) rW[j] = W4[t*4 + j];
  };
  pref(0);

  int tr = t >> 3, tc = t & 7;
  float acc[R][8];
  #pragma unroll
  for (int i=0;i<R;++i)
    #pragma unroll
    for (int c=0;c<8;++c) acc[i][c] = 0.f;

  for (int m=0;m<9;++m){
    __syncthreads();                 // previous compute done reading Al/Wl
    #pragma unroll
    for (int j=0;j<LA;++j){
      int e = t + j*256;
      Al[e & 63][e >> 6] = rA[j];
    }
    {
      int kk = t >> 2, c0 = (t & 3)*16;
      #pragma unroll
      for (int j=0;j<4;++j) *(float4*)&Wl[kk][c0 + 4*j] = rW[j];
    }
    if (m < 8) pref(m+1);            // next tile's global loads fly during compute
    __syncthreads();
    #pragma unroll 4
    for (int kk=0;kk<64;++kk){
      float a[R];
      #pragma unroll
      for (int i=0;i<R;++i) a[i] = Al[kk][tr*R + i];
      float w[8];
      *(float4*)&w[0] = *(const float4*)&Wl[kk][tc*8];
      *(float4*)&w[4] = *(const float4*)&Wl[kk][tc*8+4];
      #pragma unroll
      for (int i=0;i<R;++i)
        #pragma unroll
        for (int c=0;c<8;++c) acc[i][c] += a[i]*w[c];
    }
  }
  float bias[8];
  #pragma unroll
  for (int c=0;c<8;++c) bias[c] = Bb[tc*8+c];
  #pragma unroll
  for (int i=0;i<R;++i){
    int node = nb + tr*R + i;
    if (node >= N) continue;
    float ov[8];
    #pragma unroll
    for (int c=0;c<8;++c){
      float v = acc[i][c] + bias[c];
      ov[c] = v > 0.f ? v : 0.f;
    }
    float* dst = &h[(size_t)(off + node)*64 + tc*8];
    *(float4*)dst       = *(const float4*)&ov[0];
    *(float4*)(dst + 4) = *(const float4*)&ov[4];
  }
}

// ---------- fused tail: d=4..1 (pools + convs L=3..1 + final L=0 add), one block ----------
__global__ __launch_bounds__(256) void k_tail(float* __restrict__ h,
    const float* __restrict__ convW, const float* __restrict__ convB){
  __shared__ float P[64][65];    // pooled hd1 [ch][node], nodes <= 64
  __shared__ float Wl[64][68];
  int t = threadIdx.x;
  for (int d = 4; d >= 1; --d){
    int L = d - 1;
    int Np = 1 << (2*L);         // 64,16,4,1
    for (int e = t; e < Np*64; e += 256){
      int node = e >> 6, ch = e & 63;
      const float* c0 = h + (size_t)(OFFS[d] + 4*node)*64 + ch;
      float s = 0.25f*(c0[0] + c0[64] + c0[128] + c0[192]);
      P[ch][node] = s + h[(size_t)(OFFS[L] + node)*64 + ch];
    }
    __syncthreads();
    if (L == 0){
      if (t < 64) h[t] = P[t][0];     // OFFS[0]==0
      break;
    }
    int node = t >> 2;           // 0..63
    int c0 = (t & 3) * 16;
    bool act = node < Np;
    float acc[16];
    #pragma unroll
    for (int q=0;q<16;++q) acc[q] = 0.f;
    int res = 1 << L;
    unsigned ix = 0, iy = 0;
    if (act){ ix = deint((unsigned)node); iy = deint(((unsigned)node) >> 1); }
    const float* Wd = convW + (size_t)L*576*64;
    for (int m=0;m<9;++m){
      __syncthreads();           // prev compute done reading Wl
      for (int e = t; e < 4096; e += 256)
        Wl[e >> 6][e & 63] = Wd[(size_t)m*4096 + e];
      __syncthreads();
      if (act){
        int dy = m/3 - 1, dx = m%3 - 1;
        int nx = (int)ix + dx, ny = (int)iy + dy;
        if (nx >= 0 && ny >= 0 && nx < res && ny < res){
          int key = (int)(ileave((unsigned)nx) | (ileave((unsigned)ny) << 1));
          #pragma unroll 4
          for (int kk=0;kk<64;++kk){
            float a = P[kk][key];
            #pragma unroll
            for (int q=0;q<16;++q) acc[q] += a * Wl[kk][c0+q];
          }
        }
      }
    }
    __syncthreads();             // everyone done reading P before stores/overwrite
    if (act){
      #pragma unroll
      for (int q=0;q<16;++q){
        float v = acc[q] + convB[L*64 + c0 + q];
        h[(size_t)(OFFS[L] + node)*64 + c0 + q] = v > 0.f ? v : 0.f;
      }
    }
    __syncthreads();             // h[L] visible to next pool (same block)
  }
}

// ---------- emb + layernorm + gain, in place over h ----------
__global__ __launch_bounds__(256) void k_emb(float* h, const float* __restrict__ embW,
    const float* __restrict__ embB, const float* __restrict__ lng,
    const float* __restrict__ lnb, const float* __restrict__ gain){
  int bb = blockIdx.x;
  int d = 0;
  #pragma unroll
  for (int i = 1; i <= 9; ++i) if (bb >= EBLK[i]) d = i;
  int nb = (bb - EBLK[d]) * 128;
  int N = 1 << (2*d);
  int off = OFFS[d];

  __shared__ float Al[64][129];   // [k][node]
  __shared__ float Wl[64][68];    // [k][ch]
  int t = threadIdx.x;
  for (int idx = t; idx < 64*128; idx += 256){
    int k = idx & 63, node = idx >> 6;       // lanes = k: coalesced 256B row reads
    int g = nb + node;
    Al[k][node] = (g < N) ? h[(size_t)(off + g)*64 + k] : 0.f;
  }
  const float* Wd = embW + (size_t)d*64*64;
  for (int idx = t; idx < 64*64; idx += 256){
    int k = idx >> 6, c = idx & 63;
    Wl[k][c] = Wd[k*64 + c];
  }
  __syncthreads();
  int tr = t >> 3, tc = t & 7;
  float acc[4][8];
  #pragma unroll
  for (int i=0;i<4;++i)
    #pragma unroll
    for (int c=0;c<8;++c) acc[i][c] = embB[d*64 + tc*8 + c];
  #pragma unroll 4
  for (int k=0;k<64;++k){
    float a[4];
    #pragma unroll
    for (int i=0;i<4;++i) a[i] = Al[k][tr*4 + i];
    float w[8];
    *(float4*)&w[0] = *(const float4*)&Wl[k][tc*8];
    *(float4*)&w[4] = *(const float4*)&Wl[k][tc*8+4];
    #pragma unroll
    for (int i=0;i<4;++i)
      #pragma unroll
      for (int c=0;c<8;++c) acc[i][c] += a[i]*w[c];
  }
  float gvals[8], bvals[8];
  #pragma unroll
  for (int c=0;c<8;++c){
    gvals[c] = lng[d*64 + tc*8 + c];
    bvals[c] = lnb[d*64 + tc*8 + c];
  }
  float gn = gain[d];
  #pragma unroll
  for (int i=0;i<4;++i){
    float s = 0.f, q = 0.f;
    #pragma unroll
    for (int c=0;c<8;++c){ s += acc[i][c]; q += acc[i][c]*acc[i][c]; }
    #pragma unroll
    for (int msk = 1; msk < 8; msk <<= 1){
      s += __shfl_xor(s, msk, 64);
      q += __shfl_xor(q, msk, 64);
    }
    float mu = s * 0.015625f;
    float var = q * 0.015625f - mu*mu;
    float rs = rsqrtf(var + 1e-5f);
    int node = nb + tr*4 + i;
    if (node < N){
      float ov[8];
      #pragma unroll
      for (int c=0;c<8;++c)
        ov[c] = ((acc[i][c] - mu) * rs * gvals[c] + bvals[c]) * gn;
      float* dst = &h[(size_t)(off + node)*64 + tc*8];
      *(float4*)dst       = *(const float4*)&ov[0];
      *(float4*)(dst + 4) = *(const float4*)&ov[4];
    }
  }
}

extern "C" void kernel_launch(void* const* d_in, const int* in_sizes, int n_in,
                              void* d_out, int out_size, void* d_ws, size_t ws_size,
                              hipStream_t stream) {
  (void)in_sizes; (void)n_in; (void)out_size; (void)ws_size;
  const float* feat  = (const float*)d_in[0];
  const float* ipW   = (const float*)d_in[1];
  const float* ipB   = (const float*)d_in[2];
  const float* convW = (const float*)d_in[3];
  const float* convB = (const float*)d_in[4];
  const float* embW  = (const float*)d_in[5];
  const float* embB  = (const float*)d_in[6];
  const float* lng   = (const float*)d_in[7];
  const float* lnb   = (const float*)d_in[8];
  const float* gain  = (const float*)d_in[9];
  float* h   = (float*)d_out;          // h lives in d_out (f32), emb runs in place
  float* stg = (float*)d_ws;           // f32 pooled staging, max 16.8 MB

  k_inproj<<<(TOTAL + 127)/128, 256, 0, stream>>>(feat, ipW, ipB, h);

  // levels d=9..5: pool -> stg, conv L=d-1 (L=8..4)
  for (int d = 9; d >= 5; --d){
    int L = d - 1;
    int Np = 1 << (2*L);
    k_pool<<<(Np*64 + 255)/256, 256, 0, stream>>>(h, stg, Np, OFFS[L], OFFS[d]);
    if (L == 8){
      k_conv<128><<<(Np + 127)/128, 256, 0, stream>>>(stg,
          convW + (size_t)L*576*64, convB + (size_t)L*64, h, Np, OFFS[L], L);
    } else {
      k_conv<64><<<(Np + 63)/64, 256, 0, stream>>>(stg,
          convW + (size_t)L*576*64, convB + (size_t)L*64, h, Np, OFFS[L], L);
    }
  }

  // d=4..1 fused single-block tail (pools + convs L=3..1 + final L=0 add)
  k_tail<<<1, 256, 0, stream>>>(h, convW, convB);

  k_emb<<<2734, 256, 0, stream>>>(h, embW, embB, lng, lnb, gain);
}